// Round 5
// baseline (116.736 us; speedup 1.0000x reference)
//
#include <hip/hip_runtime.h>
#include <hip/hip_bf16.h>
#include <math.h>

// Problem constants (fixed by setup_inputs): B=128, P=4096, L=128
#define BB 128
#define PP 4096
#define LL 128
#define BLOCK 256
#define CHUNKS (PP / BLOCK)   // 16 blocks per batch -> 2048 blocks, 8192 waves
#define SCALE 32.0f
#define LCHUNK 8              // labels per unrolled chunk

// Prep: labp[b][l][8] = (x, y, x2, y2, area, w, h, pad). Moves the per-label
// uniform float math (no scalar-float ALU on CDNA!) out of the 67M-iter loop.
__global__ __launch_bounds__(256) void prep_labels_kernel(
    const float* __restrict__ labels, float* __restrict__ labp)
{
    int i = blockIdx.x * 256 + threadIdx.x;   // over B*L
    if (i < BB * LL) {
        const float* lp = labels + (size_t)i * 4;
        float x = lp[0], y = lp[1], w = lp[2], h = lp[3];
        float* o = labp + (size_t)i * 8;
        o[0] = x;
        o[1] = y;
        o[2] = x + w;     // same fp32 op as reference -> bit-identical
        o[3] = y + h;
        o[4] = w * h;
        o[5] = w;
        o[6] = h;
        o[7] = 0.0f;
    }
}

__global__ __launch_bounds__(BLOCK) void classifier_loss_kernel(
    const float* __restrict__ cls,     // [B, 2P]
    const float* __restrict__ bbox,    // [B, 4P]
    const float* __restrict__ roi,     // [B, P, 4]
    const float* __restrict__ labp,    // [B, L, 8] precomputed
    const int* __restrict__ neg_enabled,
    float* __restrict__ out)
{
    __shared__ float s_red[BLOCK / 64];

    const int b     = blockIdx.x >> 4;          // / CHUNKS
    const int chunk = blockIdx.x & (CHUNKS - 1);
    const int p     = chunk * BLOCK + threadIdx.x;

    // Wave-uniform base -> all label-field reads become s_load batches
    const float* __restrict__ lb = labp + (size_t)b * LL * 8;

    // Proposal box in image coords
    const float* rp = roi + ((size_t)b * PP + p) * 4;
    const float rx = rp[0] * SCALE, ry = rp[1] * SCALE;
    const float rw = rp[2] * SCALE, rh = rp[3] * SCALE;
    const float rx2 = rx + rw, ry2 = ry + rh;
    const float rarea = rw * rh;

    // --- argmax IoU over labels, division-free ---
    // c_i = inter/(S_i + R) = iou/(1+iou) monotone in iou -> same argmax.
    // Cross-multiplied strict compare keeps first-max (JAX argmax) semantics.
    // Init bi=-1, bd=1 so label 0 always wins the first compare.
    float best_inter = -1.0f, best_denom = 1.0f;
    int   best_idx = 0;

    for (int lc = 0; lc < LL; lc += LCHUNK) {
        #pragma unroll
        for (int u = 0; u < LCHUNK; ++u) {
            const int li = lc + u;
            // Each VALU op below pairs ONE uniform (SGPR) operand with one
            // VGPR operand -> no v_mov traffic.
            const float s_x    = lb[li * 8 + 0];
            const float s_y    = lb[li * 8 + 1];
            const float s_x2   = lb[li * 8 + 2];
            const float s_y2   = lb[li * 8 + 3];
            const float s_area = lb[li * 8 + 4];
            float ix = fmaxf(0.0f, fminf(s_x2, rx2) - fmaxf(s_x, rx));
            float iy = fmaxf(0.0f, fminf(s_y2, ry2) - fmaxf(s_y, ry));
            float inter = ix * iy;
            float denom = s_area + rarea;
            bool gt = inter * best_denom > best_inter * denom;
            best_inter = gt ? inter : best_inter;
            best_denom = gt ? denom : best_denom;
            best_idx   = gt ? li    : best_idx;
        }
    }

    const bool pos = (best_inter > 0.0f) && (best_idx > 0);  // any_hit && match>0

    // --- classification CE (softmax over 2 classes) ---
    const float s0 = cls[(size_t)b * 2 * PP + p];
    const float s1 = cls[(size_t)b * 2 * PP + PP + p];
    const float mx = fmaxf(s0, s1);
    const float e0 = expf(s0 - mx);
    const float e1 = expf(s1 - mx);
    const float inv = 1.0f / (e0 + e1);
    const float p0 = e0 * inv, p1 = e1 * inv;
    const float LOG01 = -2.3025850929940457f;  // log(0.1)
    const float LOG09 = -0.10536051565782628f; // log(0.9)
    const float ce_pos = -(p0 * LOG01 + p1 * LOG09);
    const float ce_neg = -(p0 * LOG09 + p1 * LOG01);

    float per;
    if (pos) {
        // Divergent (per-lane) gather from labp, executed once per thread
        const float* mp = lb + best_idx * 8;
        float mxl = mp[0], myl = mp[1], mwl = mp[5], mhl = mp[6];
        float tx = (mxl - rx) / rw;
        float ty = (myl - ry) / rh;
        float tw = logf(fmaxf(mwl / rw, 1e-8f));
        float th = logf(fmaxf(mhl / rh, 1e-8f));
        const float* bp = bbox + (size_t)b * 4 * PP + p;
        float ex = tx - bp[0];
        float ey = ty - bp[PP];
        float ew = tw - bp[2 * PP];
        float eh = th - bp[3 * PP];
        float ax = fabsf(ex), ay = fabsf(ey), aw = fabsf(ew), ah = fabsf(eh);
        float hx = (ax <= 1.0f) ? 0.5f * ex * ex : ax - 0.5f;
        float hy = (ay <= 1.0f) ? 0.5f * ey * ey : ay - 0.5f;
        float hw = (aw <= 1.0f) ? 0.5f * ew * ew : aw - 0.5f;
        float hh = (ah <= 1.0f) ? 0.5f * eh * eh : ah - 0.5f;
        float huber = 0.25f * (hx + hy + hw + hh);
        per = 2.0f * huber + ce_pos;
    } else {
        per = (neg_enabled[0] > 0) ? ce_neg : 0.0f;
    }

    // --- reduce: wave64 shuffle -> LDS -> one atomic per block ---
    float v = per;
    #pragma unroll
    for (int off = 32; off > 0; off >>= 1)
        v += __shfl_down(v, off, 64);
    if ((threadIdx.x & 63) == 0)
        s_red[threadIdx.x >> 6] = v;
    __syncthreads();
    if (threadIdx.x == 0) {
        float blk = s_red[0] + s_red[1] + s_red[2] + s_red[3];
        atomicAdd(out, blk);
    }
}

extern "C" void kernel_launch(void* const* d_in, const int* in_sizes, int n_in,
                              void* d_out, int out_size, void* d_ws, size_t ws_size,
                              hipStream_t stream) {
    const float* cls    = (const float*)d_in[0];
    const float* bbox   = (const float*)d_in[1];
    const float* roi    = (const float*)d_in[2];
    const float* labels = (const float*)d_in[3];
    const int*   neg    = (const int*)d_in[4];
    float* out  = (float*)d_out;
    float* labp = (float*)d_ws;   // 128*128*8 floats = 512 KB scratch

    hipMemsetAsync(out, 0, sizeof(float) * out_size, stream);
    prep_labels_kernel<<<dim3((BB * LL + 255) / 256), dim3(256), 0, stream>>>(
        labels, labp);
    classifier_loss_kernel<<<dim3(BB * CHUNKS), dim3(BLOCK), 0, stream>>>(
        cls, bbox, roi, labp, neg, out);
}

// Round 6
// 110.273 us; speedup vs baseline: 1.0586x; 1.0586x over previous
//
#include <hip/hip_runtime.h>
#include <hip/hip_bf16.h>
#include <math.h>

// Problem constants (fixed by setup_inputs): B=128, P=4096, L=128
#define BB 128
#define PP 4096
#define LL 128
#define BLOCK 256
#define CHUNKS (PP / BLOCK)   // 16 blocks per batch -> 2048 blocks, 8192 waves
#define SCALE 32.0f

// labp layout: [B][5][L] field-major (x, y, x2, y2, area).
// Field-major => the hot loop fetches only needed dwords, in contiguous runs
// the compiler can batch into s_load_dwordx16.
__global__ __launch_bounds__(256) void prep_labels_kernel(
    const float* __restrict__ labels, float* __restrict__ labp)
{
    int i = blockIdx.x * 256 + threadIdx.x;   // over B*L
    if (i < BB * LL) {
        int b = i >> 7, li = i & (LL - 1);
        const float* lp = labels + (size_t)i * 4;
        float x = lp[0], y = lp[1], w = lp[2], h = lp[3];
        float* o = labp + (size_t)b * (5 * LL) + li;
        o[0 * LL] = x;
        o[1 * LL] = y;
        o[2 * LL] = x + w;     // same fp32 ops as reference -> bit-identical
        o[3 * LL] = y + h;
        o[4 * LL] = w * h;
    }
}

__global__ __launch_bounds__(BLOCK) void classifier_loss_kernel(
    const float* __restrict__ cls,     // [B, 2P]
    const float* __restrict__ bbox,    // [B, 4P]
    const float* __restrict__ roi,     // [B, P, 4]
    const float* __restrict__ labp,    // [B, 5, L] precomputed field-major
    const float* __restrict__ labels,  // [B, L, 4] raw (epilogue gather only)
    const int* __restrict__ neg_enabled,
    float* __restrict__ out)
{
    __shared__ float s_red[BLOCK / 64];

    const int b     = blockIdx.x >> 4;          // / CHUNKS
    const int chunk = blockIdx.x & (CHUNKS - 1);
    const int p     = chunk * BLOCK + threadIdx.x;

    // Wave-uniform base -> label-field reads become batched s_loads
    const float* __restrict__ lb = labp + (size_t)b * (5 * LL);

    // Prefetch per-thread VMEM early so HBM latency hides under the IoU loop
    const float* rp = roi + ((size_t)b * PP + p) * 4;
    const float r0 = rp[0], r1 = rp[1], r2 = rp[2], r3 = rp[3];
    const float s0 = cls[(size_t)b * 2 * PP + p];
    const float s1 = cls[(size_t)b * 2 * PP + PP + p];

    const float rx = r0 * SCALE, ry = r1 * SCALE;
    const float rw = r2 * SCALE, rh = r3 * SCALE;
    const float rx2 = rx + rw, ry2 = ry + rh;
    const float rarea = rw * rh;

    // --- argmax IoU over labels, division-free ---
    // c_i = inter/(S_i + R) = iou/(1+iou) is monotone in iou -> same argmax.
    // Cross-multiplied strict '>' keeps first-max (JAX argmax) semantics.
    // Init bi=-1, bd=1 so label 0 always wins the first compare.
    float best_inter = -1.0f, best_denom = 1.0f;
    int   best_idx = 0;

    // FULL unroll: straight-line code lets the scheduler spread s_loads far
    // ahead of use (partial lgkmcnt waits) instead of per-chunk full drains.
    #pragma unroll
    for (int li = 0; li < LL; ++li) {
        const float s_x    = lb[0 * LL + li];
        const float s_y    = lb[1 * LL + li];
        const float s_x2   = lb[2 * LL + li];
        const float s_y2   = lb[3 * LL + li];
        const float s_area = lb[4 * LL + li];
        float ix = fmaxf(0.0f, fminf(s_x2, rx2) - fmaxf(s_x, rx));
        float iy = fmaxf(0.0f, fminf(s_y2, ry2) - fmaxf(s_y, ry));
        float inter = ix * iy;
        float denom = s_area + rarea;
        bool gt = inter * best_denom > best_inter * denom;
        best_inter = gt ? inter : best_inter;
        best_denom = gt ? denom : best_denom;
        best_idx   = gt ? li    : best_idx;
    }

    const bool pos = (best_inter > 0.0f) && (best_idx > 0);  // any_hit && match>0

    // --- classification CE (softmax over 2 classes) ---
    const float mx = fmaxf(s0, s1);
    const float e0 = expf(s0 - mx);
    const float e1 = expf(s1 - mx);
    const float inv = 1.0f / (e0 + e1);
    const float p0 = e0 * inv, p1 = e1 * inv;
    const float LOG01 = -2.3025850929940457f;  // log(0.1)
    const float LOG09 = -0.10536051565782628f; // log(0.9)
    const float ce_pos = -(p0 * LOG01 + p1 * LOG09);
    const float ce_neg = -(p0 * LOG09 + p1 * LOG01);

    float per;
    if (pos) {
        // Divergent per-lane gather from raw labels, executed once per thread
        const float* mp = labels + ((size_t)b * LL + best_idx) * 4;
        float mxl = mp[0], myl = mp[1], mwl = mp[2], mhl = mp[3];
        float tx = (mxl - rx) / rw;
        float ty = (myl - ry) / rh;
        float tw = logf(fmaxf(mwl / rw, 1e-8f));
        float th = logf(fmaxf(mhl / rh, 1e-8f));
        const float* bp = bbox + (size_t)b * 4 * PP + p;
        float ex = tx - bp[0];
        float ey = ty - bp[PP];
        float ew = tw - bp[2 * PP];
        float eh = th - bp[3 * PP];
        float ax = fabsf(ex), ay = fabsf(ey), aw = fabsf(ew), ah = fabsf(eh);
        float hx = (ax <= 1.0f) ? 0.5f * ex * ex : ax - 0.5f;
        float hy = (ay <= 1.0f) ? 0.5f * ey * ey : ay - 0.5f;
        float hw = (aw <= 1.0f) ? 0.5f * ew * ew : aw - 0.5f;
        float hh = (ah <= 1.0f) ? 0.5f * eh * eh : ah - 0.5f;
        float huber = 0.25f * (hx + hy + hw + hh);
        per = 2.0f * huber + ce_pos;
    } else {
        per = (neg_enabled[0] > 0) ? ce_neg : 0.0f;
    }

    // --- reduce: wave64 shuffle -> LDS -> one atomic per block ---
    float v = per;
    #pragma unroll
    for (int off = 32; off > 0; off >>= 1)
        v += __shfl_down(v, off, 64);
    if ((threadIdx.x & 63) == 0)
        s_red[threadIdx.x >> 6] = v;
    __syncthreads();
    if (threadIdx.x == 0) {
        float blk = s_red[0] + s_red[1] + s_red[2] + s_red[3];
        atomicAdd(out, blk);
    }
}

extern "C" void kernel_launch(void* const* d_in, const int* in_sizes, int n_in,
                              void* d_out, int out_size, void* d_ws, size_t ws_size,
                              hipStream_t stream) {
    const float* cls    = (const float*)d_in[0];
    const float* bbox   = (const float*)d_in[1];
    const float* roi    = (const float*)d_in[2];
    const float* labels = (const float*)d_in[3];
    const int*   neg    = (const int*)d_in[4];
    float* out  = (float*)d_out;
    float* labp = (float*)d_ws;   // 128*5*128 floats = 320 KB scratch

    hipMemsetAsync(out, 0, sizeof(float) * out_size, stream);
    prep_labels_kernel<<<dim3((BB * LL + 255) / 256), dim3(256), 0, stream>>>(
        labels, labp);
    classifier_loss_kernel<<<dim3(BB * CHUNKS), dim3(BLOCK), 0, stream>>>(
        cls, bbox, roi, labp, labels, neg, out);
}